// Round 12
// baseline (28.895 us; speedup 1.0000x reference)
//
#include <hip/hip_runtime.h>

#define PNUM    1024
#define NB      128
#define NBLOCKS (NB * 16)

typedef _Float16 h2 __attribute__((ext_vector_type(2)));
typedef _Float16 h4 __attribute__((ext_vector_type(4)));

// gt LDS: pad +1 word every 8 -> b32 reads, banks (9s+4j+c)%32 = exactly 2 lanes/bank (free)
#define PW(e) ((e) + ((e) >> 3))
// pred LDS: stride-34 rows of 32 elements -> b64 reads, bank-pairs 2j distinct.

// smooth-L1 via clamp identity: m = clamp(d,-1,1); sl1(d) = m*(d - 0.5m). 5 packed ops.
#define SL1(acc, p, g) do {                               \
    h2 d_ = (p) - (g);                                    \
    h2 m_ = __builtin_elementwise_min(                    \
              __builtin_elementwise_max(d_, none2), one2);\
    h2 t_ = __builtin_elementwise_fma(m_, nh2, d_);       \
    (acc) = __builtin_elementwise_fma(m_, t_, (acc)); } while (0)

// Pipelined group: window q0..q10 = gt elements e0..e0+10 (ALL already in regs);
// issues loads for NEXT group (gt e0+11..14 into q11..q14, pred e0+4..7 into NPA/NPB)
// BEFORE the 160 VALU ops -> load-use distance ~160 ops instead of ~14.
#define GROUP15(e0, q0,q1,q2,q3,q4,q5,q6,q7,q8,q9,q10,q11,q12,q13,q14, CPA,CPB,NPA,NPB) do { \
    q11 = Gp[PW((e0)+11)]; q12 = Gp[PW((e0)+12)];                    \
    q13 = Gp[PW((e0)+13)]; q14 = Gp[PW((e0)+14)];                    \
    NPA = *(const h4*)(Pp + (e0) + 4);                               \
    NPB = *(const h4*)(Pp + (e0) + 6);                               \
    h2 p0 = CPA.lo, p1 = CPA.hi, p2 = CPB.lo, p3 = CPB.hi;           \
    SL1(a0,p0,q0); SL1(a1,p0,q1); SL1(a2,p0,q2); SL1(a3,p0,q3);      \
    SL1(a4,p0,q4); SL1(a5,p0,q5); SL1(a6,p0,q6); SL1(a7,p0,q7);      \
    SL1(a0,p1,q1); SL1(a1,p1,q2); SL1(a2,p1,q3); SL1(a3,p1,q4);      \
    SL1(a4,p1,q5); SL1(a5,p1,q6); SL1(a6,p1,q7); SL1(a7,p1,q8);      \
    SL1(a0,p2,q2); SL1(a1,p2,q3); SL1(a2,p2,q4); SL1(a3,p2,q5);      \
    SL1(a4,p2,q6); SL1(a5,p2,q7); SL1(a6,p2,q8); SL1(a7,p2,q9);      \
    SL1(a0,p3,q3); SL1(a1,p3,q4); SL1(a2,p3,q5); SL1(a3,p3,q6);      \
    SL1(a4,p3,q7); SL1(a5,p3,q8); SL1(a6,p3,q9); SL1(a7,p3,q10);     \
  } while (0)

// Last group: no prefetch.
#define GROUP15L(e0, q0,q1,q2,q3,q4,q5,q6,q7,q8,q9,q10, CPA,CPB) do { \
    h2 p0 = CPA.lo, p1 = CPA.hi, p2 = CPB.lo, p3 = CPB.hi;           \
    SL1(a0,p0,q0); SL1(a1,p0,q1); SL1(a2,p0,q2); SL1(a3,p0,q3);      \
    SL1(a4,p0,q4); SL1(a5,p0,q5); SL1(a6,p0,q6); SL1(a7,p0,q7);      \
    SL1(a0,p1,q1); SL1(a1,p1,q2); SL1(a2,p1,q3); SL1(a3,p1,q4);      \
    SL1(a4,p1,q5); SL1(a5,p1,q6); SL1(a6,p1,q7); SL1(a7,p1,q8);      \
    SL1(a0,p2,q2); SL1(a1,p2,q3); SL1(a2,p2,q4); SL1(a3,p2,q5);      \
    SL1(a4,p2,q6); SL1(a5,p2,q7); SL1(a6,p2,q8); SL1(a7,p2,q9);      \
    SL1(a0,p3,q3); SL1(a1,p3,q4); SL1(a2,p3,q5); SL1(a3,p3,q6);      \
    SL1(a4,p3,q7); SL1(a5,p3,q8); SL1(a6,p3,q9); SL1(a7,p3,q10);     \
  } while (0)

// One block = (batch b, 64 consecutive shifts). 256 threads =
// 8 shift-slots (8 shifts each, 15-wide pipelined gt window) x 32 j-slots (32 j each).
// NO atomics (R8: fused agent-scope atomic tail collapses codegen to 20 VGPR).
__global__ __launch_bounds__(256, 8) void poly_cost_kernel(
    const float* __restrict__ pred, const float* __restrict__ gt,
    float* __restrict__ block_min) {
  __shared__ h2    pred_s[1088];     // 32 rows x 34 words
  __shared__ h2    gt_s[1223];       // PW(1087)=1222
  __shared__ float partial[4][64];

  const int b     = blockIdx.x >> 4;
  const int chunk = blockIdx.x & 15;
  const int t     = threadIdx.x;

  const float4* pred4 = (const float4*)(pred + (size_t)b * (PNUM * 2));
  const float4* gt4   = (const float4*)(gt   + (size_t)b * (PNUM * 2));
  const int gb2 = chunk * 32;        // gt float4 base

  #pragma unroll
  for (int r = 0; r < 2; ++r) {
    int p = t + r * 256;             // float4 index = h2 elements 2p, 2p+1
    float4 v = pred4[p];
    int w = 34 * (p >> 4) + ((2 * p) & 31);
    pred_s[w]     = h2{(_Float16)v.x, (_Float16)v.y};
    pred_s[w + 1] = h2{(_Float16)v.z, (_Float16)v.w};
  }
  #pragma unroll
  for (int r = 0; r < 2; ++r) {
    int u = t + r * 256;
    float4 v = gt4[(gb2 + u) & 511];
    int w = PW(2 * u);               // 2u even -> pair never crosses pad boundary
    gt_s[w]     = h2{(_Float16)v.x, (_Float16)v.y};
    gt_s[w + 1] = h2{(_Float16)v.z, (_Float16)v.w};
  }
  if (t < 32) {
    int u = t + 512;
    float4 v = gt4[(gb2 + u) & 511];
    int w = PW(2 * u);
    gt_s[w]     = h2{(_Float16)v.x, (_Float16)v.y};
    gt_s[w + 1] = h2{(_Float16)v.z, (_Float16)v.w};
  }
  __syncthreads();

  const int sslot = t & 7;           // shifts i = chunk*64 + sslot*8 + s, s=0..7
  const int jslot = t >> 3;          // j = jslot*32 + jj, jj=0..31
  const h2* Pp = pred_s + 34 * jslot;             // stride-34 pred row
  const h2* Gp = gt_s   + 9 * sslot + 36 * jslot; // PW(8*sslot+32*jslot)

  const h2 one2  = {(_Float16)1.0f,  (_Float16)1.0f};
  const h2 none2 = {(_Float16)-1.0f, (_Float16)-1.0f};
  const h2 nh2   = {(_Float16)-0.5f, (_Float16)-0.5f};
  h2 a0 = {(_Float16)0.0f, (_Float16)0.0f};
  h2 a1 = a0, a2 = a0, a3 = a0, a4 = a0, a5 = a0, a6 = a0, a7 = a0;

  // prologue: preload gt elements 0..10 and pred elements 0..3
  h2 m0 = Gp[PW(0)], m1 = Gp[PW(1)], m2 = Gp[PW(2)], m3 = Gp[PW(3)];
  h2 m4 = Gp[PW(4)], m5 = Gp[PW(5)], m6 = Gp[PW(6)], m7 = Gp[PW(7)];
  h2 m8 = Gp[PW(8)], m9 = Gp[PW(9)], m10 = Gp[PW(10)];
  h2 m11, m12, m13, m14;
  h4 cpa = *(const h4*)(Pp), cpb = *(const h4*)(Pp + 2);
  h4 dpa, dpb;

  // rotation by 4 mod 15: window starts 0,4,8,12,1,5,9,13
  GROUP15( 0, m0,m1,m2,m3,m4,m5,m6,m7,m8,m9,m10,m11,m12,m13,m14, cpa,cpb,dpa,dpb);
  GROUP15( 4, m4,m5,m6,m7,m8,m9,m10,m11,m12,m13,m14,m0,m1,m2,m3, dpa,dpb,cpa,cpb);
  GROUP15( 8, m8,m9,m10,m11,m12,m13,m14,m0,m1,m2,m3,m4,m5,m6,m7, cpa,cpb,dpa,dpb);
  GROUP15(12, m12,m13,m14,m0,m1,m2,m3,m4,m5,m6,m7,m8,m9,m10,m11, dpa,dpb,cpa,cpb);
  GROUP15(16, m1,m2,m3,m4,m5,m6,m7,m8,m9,m10,m11,m12,m13,m14,m0, cpa,cpb,dpa,dpb);
  GROUP15(20, m5,m6,m7,m8,m9,m10,m11,m12,m13,m14,m0,m1,m2,m3,m4, dpa,dpb,cpa,cpb);
  GROUP15(24, m9,m10,m11,m12,m13,m14,m0,m1,m2,m3,m4,m5,m6,m7,m8, cpa,cpb,dpa,dpb);
  GROUP15L(28, m13,m14,m0,m1,m2,m3,m4,m5,m6,m7,m8, dpa,dpb);

  // ---- reduce over jslot (lane bits 3..5) via shuffles, named floats only
  float f0 = (float)a0.x + (float)a0.y, f1 = (float)a1.x + (float)a1.y;
  float f2 = (float)a2.x + (float)a2.y, f3 = (float)a3.x + (float)a3.y;
  float f4 = (float)a4.x + (float)a4.y, f5 = (float)a5.x + (float)a5.y;
  float f6 = (float)a6.x + (float)a6.y, f7 = (float)a7.x + (float)a7.y;
#define JRED(f) f += __shfl_xor(f, 8); f += __shfl_xor(f, 16); f += __shfl_xor(f, 32)
  JRED(f0); JRED(f1); JRED(f2); JRED(f3); JRED(f4); JRED(f5); JRED(f6); JRED(f7);
#undef JRED

  const int wid = t >> 6, lane = t & 63;
  if ((lane & 56) == 0) {            // lanes 0..7: sslot = lane
    float* pp = &partial[wid][lane * 8];
    pp[0] = f0; pp[1] = f1; pp[2] = f2; pp[3] = f3;
    pp[4] = f4; pp[5] = f5; pp[6] = f6; pp[7] = f7;
  }
  __syncthreads();

  // ---- per-block: sum 4 wave-partials per shift, min over 64 shifts
  if (t < 64) {
    float sum = partial[0][t] + partial[1][t] + partial[2][t] + partial[3][t];
    float dis = sum * (1.0f / 1024.0f);
    #pragma unroll
    for (int off = 32; off; off >>= 1)
      dis = fminf(dis, __shfl_xor(dis, off));
    if (t == 0) block_min[blockIdx.x] = dis;   // plain store, no atomics
  }
}

// Kernel 2: per-batch min over 16 block-mins, then mean over 128 batches.
__global__ __launch_bounds__(128) void poly_reduce_kernel(
    const float* __restrict__ block_min, float* __restrict__ out) {
  const int b = threadIdx.x;
  float m = block_min[b * 16];
  #pragma unroll
  for (int c = 1; c < 16; ++c) m = fminf(m, block_min[b * 16 + c]);
  #pragma unroll
  for (int off = 32; off; off >>= 1) m += __shfl_xor(m, off);
  __shared__ float wsum[2];
  if ((b & 63) == 0) wsum[b >> 6] = m;
  __syncthreads();
  if (b == 0) out[0] = (wsum[0] + wsum[1]) * (1.0f / NB);
}

extern "C" void kernel_launch(void* const* d_in, const int* in_sizes, int n_in,
                              void* d_out, int out_size, void* d_ws, size_t ws_size,
                              hipStream_t stream) {
  const float* pred = (const float*)d_in[0];
  const float* gt   = (const float*)d_in[1];
  float* out        = (float*)d_out;
  float* block_min  = (float*)d_ws;   // 2048 floats

  poly_cost_kernel<<<NBLOCKS, 256, 0, stream>>>(pred, gt, block_min);
  poly_reduce_kernel<<<1, 128, 0, stream>>>(block_min, out);
}